// Round 9
// baseline (169.572 us; speedup 1.0000x reference)
//
#include <hip/hip_runtime.h>
#include <hip/hip_bf16.h>
#include <math.h>

// Problem constants (B=2, T=2048, C=1024, NH=16, HS=64)
#define BB   2
#define TT   2048
#define CC   1024
#define NH   16
#define HS   64
#define N3C  3072   // 3*C
#define MM   4096   // B*T

typedef __attribute__((ext_vector_type(8))) short bf16x8;
typedef __attribute__((ext_vector_type(4))) float f32x4;

#define NINF (-__builtin_inff())
#define QSCALE 0.125f   /* folded 1/sqrt(HS); softmax via __expf (natural e) */

__device__ __forceinline__ unsigned short f2bf(float f) {
    unsigned int u = __builtin_bit_cast(unsigned int, f);
    unsigned int r = u + 0x7fffu + ((u >> 16) & 1u);   // RNE
    return (unsigned short)(r >> 16);
}

// cheap round-to-nearest (no tie-to-even) — used only for P (positive, bounded)
__device__ __forceinline__ unsigned short f2bf_fast(float f) {
    unsigned int u = __builtin_bit_cast(unsigned int, f);
    return (unsigned short)((u + 0x8000u) >> 16);
}

// async 16B global -> LDS (dst must be wave-uniform base + lane*16)
__device__ __forceinline__ void gl_lds16(const unsigned short* g, unsigned short* l) {
    __builtin_amdgcn_global_load_lds(
        (const __attribute__((address_space(1))) unsigned int*)g,
        (__attribute__((address_space(3))) unsigned int*)l, 16, 0, 0);
}

// ---------------- cast x (fp32) -> xb (bf16) ----------------
__global__ __launch_bounds__(256) void k_cast(const float* __restrict__ x,
                                              unsigned short* __restrict__ xb) {
    int i = (blockIdx.x * 256 + threadIdx.x) * 4;
    float4 v = *(const float4*)(x + i);
    ushort4 o;
    o.x = f2bf(v.x); o.y = f2bf(v.y); o.z = f2bf(v.z); o.w = f2bf(v.w);
    *(ushort4*)(xb + i) = o;
}

// ---------------- transpose+cast W [K=1024, N=3072] -> Wt [N, K] bf16 ----------------
__global__ __launch_bounds__(256) void k_transpose_w(const float* __restrict__ W,
                                                     unsigned short* __restrict__ Wt) {
    __shared__ float tile[32][33];
    const int n0 = blockIdx.x * 32;
    const int k0 = blockIdx.y * 32;
    const int t = threadIdx.x;
    {
        int kr = t >> 3, ns = (t & 7) * 4;
        float4 v = *(const float4*)(W + (size_t)(k0 + kr) * N3C + n0 + ns);
        tile[kr][ns + 0] = v.x; tile[kr][ns + 1] = v.y;
        tile[kr][ns + 2] = v.z; tile[kr][ns + 3] = v.w;
    }
    __syncthreads();
    {
        int nr = t >> 3, ks = (t & 7) * 4;
        ushort4 o;
        o.x = f2bf(tile[ks + 0][nr]);
        o.y = f2bf(tile[ks + 1][nr]);
        o.z = f2bf(tile[ks + 2][nr]);
        o.w = f2bf(tile[ks + 3][nr]);
        *(ushort4*)(Wt + (size_t)(n0 + nr) * CC + k0 + ks) = o;
    }
}

// ---------------- GEMM v2 (r7-proven): 128x128 tile, BK=64, XOR-swizzled LDS,
// LDS union (sA+sB overlaid by sE epilogue), coalesced epilogues. ----------------
#define EPS 72   // epilogue LDS row stride (elements): 144B, 16B-aligned

__global__ __launch_bounds__(256) void k_gemm_qkv(const unsigned short* __restrict__ xb,
                                                  const unsigned short* __restrict__ wt,
                                                  const float* __restrict__ bias,
                                                  unsigned short* __restrict__ qb,
                                                  unsigned short* __restrict__ kb,
                                                  unsigned short* __restrict__ vt) {
    __shared__ unsigned short smem[4 * 64 * EPS];   // 36864 B union
    unsigned short* sA = smem;                      // [128][64] during k-loop (16 KB)
    unsigned short* sB = smem + 128 * 64;           // [128][64] during k-loop (16 KB)
    unsigned short* sE = smem;                      // 4 x [64][EPS] epilogue staging (36 KB)

    const int t = threadIdx.x;
    const int wave = t >> 6, lane = t & 63;
    const int quad = lane >> 4, c16 = lane & 15;
    const int wm = wave >> 1, wn = wave & 1;
    const int m0 = blockIdx.y * 128;
    const int n0 = blockIdx.x * 128;
    const int sel = n0 >> 10;                 // block-uniform: 0=q, 1=k, 2=v

    f32x4 acc[4][4];
#pragma unroll
    for (int i = 0; i < 4; ++i)
#pragma unroll
        for (int j = 0; j < 4; ++j) acc[i][j] = f32x4{0, 0, 0, 0};

    const int srow_ = t >> 3;                 // 0..31 (row within a 32-row round)
    const int sslot = t & 7;                  // 16B slot within 128B row

    for (int k0 = 0; k0 < CC; k0 += 64) {
        __syncthreads();
#pragma unroll
        for (int rnd = 0; rnd < 4; ++rnd) {
            const int row = rnd * 32 + srow_;
            const int sl = (sslot ^ (row & 7)) * 8;           // pre-swizzled global elem offset
            gl_lds16(xb + (size_t)(m0 + row) * CC + k0 + sl, sA + rnd * 2048 + t * 8);
            gl_lds16(wt + (size_t)(n0 + row) * CC + k0 + sl, sB + rnd * 2048 + t * 8);
        }
        __syncthreads();
#pragma unroll
        for (int ks = 0; ks < 2; ++ks) {
            bf16x8 a[4], b[4];
#pragma unroll
            for (int rt = 0; rt < 4; ++rt)
                a[rt] = *(const bf16x8*)(sA + (wm * 64 + rt * 16 + c16) * 64 +
                                         (((ks * 4 + quad) ^ (c16 & 7)) * 8));
#pragma unroll
            for (int ct = 0; ct < 4; ++ct)
                b[ct] = *(const bf16x8*)(sB + (wn * 64 + ct * 16 + c16) * 64 +
                                         (((ks * 4 + quad) ^ (c16 & 7)) * 8));
#pragma unroll
            for (int rt = 0; rt < 4; ++rt)
#pragma unroll
                for (int ct = 0; ct < 4; ++ct)
                    acc[rt][ct] = __builtin_amdgcn_mfma_f32_16x16x32_bf16(b[ct], a[rt], acc[rt][ct], 0, 0, 0);
        }
    }
    __syncthreads();   // union: epilogue sE overlaps sA/sB

    const int head = ((n0 + wn * 64) >> 6) & 15;           // wave-uniform
    const int bh = (m0 >> 11) * NH + head;
    const int tbase = (m0 & 2047) + wm * 64;               // this wave's 64 t-rows
    if (sel < 2) {
        unsigned short* dst = (sel == 0) ? qb : kb;
        const float sc = (sel == 0) ? QSCALE : 1.0f;
        unsigned short* ew = sE + wave * (64 * EPS);
#pragma unroll
        for (int ct = 0; ct < 4; ++ct) {
            const float4 bv4 = *(const float4*)(bias + n0 + wn * 64 + ct * 16 + quad * 4);
            const int d0 = ct * 16 + quad * 4;
#pragma unroll
            for (int rt = 0; rt < 4; ++rt) {
                ushort4 pk;
                pk.x = f2bf((acc[rt][ct][0] + bv4.x) * sc);
                pk.y = f2bf((acc[rt][ct][1] + bv4.y) * sc);
                pk.z = f2bf((acc[rt][ct][2] + bv4.z) * sc);
                pk.w = f2bf((acc[rt][ct][3] + bv4.w) * sc);
                *(ushort4*)(ew + (rt * 16 + c16) * EPS + d0) = pk;
            }
        }
        const size_t gbase = ((size_t)bh * TT + tbase) * HS;
#pragma unroll
        for (int i = 0; i < 8; ++i) {
            const int trow = i * 8 + (lane >> 3);
            bf16x8 row = *(const bf16x8*)(ew + trow * EPS + (lane & 7) * 8);
            *(bf16x8*)(dst + gbase + (size_t)trow * HS + (lane & 7) * 8) = row;
        }
    } else {
        unsigned short* ew = sE + wave * (64 * EPS);
#pragma unroll
        for (int ct = 0; ct < 4; ++ct) {
            const float4 bv4 = *(const float4*)(bias + n0 + wn * 64 + ct * 16 + quad * 4);
#pragma unroll
            for (int r = 0; r < 4; ++r) {
                const int d = ct * 16 + quad * 4 + r;
                const float bv = ((const float*)&bv4)[r];
#pragma unroll
                for (int rt = 0; rt < 4; ++rt)
                    ew[d * EPS + rt * 16 + c16] = f2bf(acc[rt][ct][r] + bv);
            }
        }
        const size_t vbase = (size_t)bh * HS * TT + tbase;
#pragma unroll
        for (int i = 0; i < 8; ++i) {
            const int d = i * 8 + (lane >> 3);
            bf16x8 row = *(const bf16x8*)(ew + d * EPS + (lane & 7) * 8);
            *(bf16x8*)(vt + vbase + (size_t)d * TT + (lane & 7) * 8) = row;
        }
    }
}

// ---------------- Flash attention v13: j=2 wave-tiles to HALVE LDS traffic per work.
// Evidence (r8): 2 barrier domains -> VALUBusy +40%, duration UNCHANGED -> limiter is a
// per-CU throughput resource. Arithmetic: 280 wave-tiles x ~360 LDS-pipe cyc = ~87% of
// wall -> LDS-pipe-bound. Fix: each wave owns 32 q-rows (round-2-proven j=2 tile():
// same kf/vf reads feed 2x MFMA work; b128 reads per unit work 36->20).
// Block = 8 waves over TWO panels CONCURRENTLY (waves 0-3: panel 15-g, waves 4-7:
// panel g; panel g's k-tiles are a subset -> proven wave-uniform guard). Block total
// wave-tiles = 4(32-2g)+4(2g+2) = 136 for every block. 256 blocks, 8 waves/CU.
// sP reused per-j (16 rows/wave; same-wave DS ordering covers the RAW/WAR) -> LDS 51200B. ----------------
#define SPP 72   // P row stride (elements): 144B, 16B-aligned

__global__ __launch_bounds__(512) void k_attn(const unsigned short* __restrict__ qb,
                                              const unsigned short* __restrict__ kb,
                                              const unsigned short* __restrict__ vt,
                                              float* __restrict__ out) {
    __shared__ unsigned short sK[2][64 * 64];   // 16 KB: K tile [row t][d], granule-swizzled
    __shared__ unsigned short sV[2][64 * 64];   // 16 KB: V^T tile [row d][t], granule-swizzled
    __shared__ unsigned short sP[8][16 * SPP];  // 18 KB: per-wave P staging (16 rows, reused per-j)

    const int tid = threadIdx.x;
    const int wave = tid >> 6, lane = tid & 63;
    const int quad = lane >> 4, c16 = lane & 15;
    const int g = blockIdx.x >> 5;              // 0..7
    const int bh = blockIdx.x & 31;
    const int p = (wave < 4) ? (15 - g) : g;    // waves 0-3: long panel; 4-7: short panel
    const int qw = p * 128 + (wave & 3) * 32;   // this wave's 32 q-rows
    const int qmax = qw + 31;
    const int kiters = 32 - 2 * g;              // covers the long panel; short is a subset

    const unsigned short* Qp = qb + (size_t)bh * TT * HS;
    const unsigned short* Kp = kb + (size_t)bh * TT * HS;
    const unsigned short* Vp = vt + (size_t)bh * HS * TT;

    unsigned short* sPw = sP[wave];

    // Q fragments (B-operand for S^T): q = qw + j*16 + c16
    bf16x8 qf[2][2];
#pragma unroll
    for (int j = 0; j < 2; ++j)
#pragma unroll
        for (int ks = 0; ks < 2; ++ks)
            qf[j][ks] = *(const bf16x8*)(Qp + (size_t)(qw + j * 16 + c16) * HS + ks * 32 + quad * 8);

    f32x4 o[4][2];                              // O^T accumulator: [dt (d)][j (q)]
#pragma unroll
    for (int dt = 0; dt < 4; ++dt)
#pragma unroll
        for (int j = 0; j < 2; ++j) o[dt][j] = f32x4{0, 0, 0, 0};
    float lsum[2] = {0.f, 0.f};

    // --- staging (r6-proven 512-thread pattern): 64 rows x 8 slots of 16B in one shot;
    // 1 K + 1 V load per thread. LDS dest LINEAR; XOR swizzle on GLOBAL source.
    const int srow = tid >> 3;                  // 0..63
    const int ssc = tid & 7;                    // 16B slot
    const int sl = (ssc ^ (srow & 7)) * 8;      // swizzled element offset
    const unsigned short* Ksrc = Kp + (size_t)srow * HS + sl;
    const unsigned short* Vsrc = Vp + (size_t)srow * TT + sl;
    auto stage = [&](int buf, int kt) {
        const int kb0 = kt * 64;
        gl_lds16(Ksrc + (size_t)kb0 * HS, &sK[buf][tid * 8]);
        gl_lds16(Vsrc + kb0, &sV[buf][tid * 8]);
    };

    auto tile = [&](int buf, int kt) {
        const int kb0 = kt * 64;
        const unsigned short* Kb = sK[buf];
        const unsigned short* Vb = sV[buf];
        // K fragments (swizzled read): row = mt*16+c16, slot = (ks*4+quad)^(c16&7)
        bf16x8 kf[4][2];
#pragma unroll
        for (int mt = 0; mt < 4; ++mt)
#pragma unroll
            for (int ks = 0; ks < 2; ++ks)
                kf[mt][ks] = *(const bf16x8*)(Kb + (mt * 16 + c16) * 64 +
                                              (((ks * 4 + quad) ^ (c16 & 7)) * 8));
        // S^T: s[mt][j], element: k = kb0+mt*16+quad*4+r, q = qw+j*16+c16
        f32x4 s[4][2];
#pragma unroll
        for (int mt = 0; mt < 4; ++mt)
#pragma unroll
            for (int j = 0; j < 2; ++j) s[mt][j] = f32x4{0, 0, 0, 0};
#pragma unroll
        for (int mt = 0; mt < 4; ++mt)
#pragma unroll
            for (int j = 0; j < 2; ++j) {
                s[mt][j] = __builtin_amdgcn_mfma_f32_16x16x32_bf16(kf[mt][0], qf[j][0], s[mt][j], 0, 0, 0);
                s[mt][j] = __builtin_amdgcn_mfma_f32_16x16x32_bf16(kf[mt][1], qf[j][1], s[mt][j], 0, 0, 0);
            }
        // V fragments issued now; consumed after softmax (vf reused for both j)
        bf16x8 vf[4][2];
#pragma unroll
        for (int dt = 0; dt < 4; ++dt)
#pragma unroll
            for (int ks = 0; ks < 2; ++ks)
                vf[dt][ks] = *(const bf16x8*)(Vb + (dt * 16 + c16) * 64 +
                                              (((ks * 4 + quad) ^ (c16 & 7)) * 8));
        const bool maskit = (kb0 + 63 > qw);
        // per-j: exp/pack -> sP (16-row buffer reused; same-wave DS ordering) -> pf read
        bf16x8 pf[2][2];
#pragma unroll
        for (int j = 0; j < 2; ++j) {
            const int rowq = qw + j * 16 + c16;
            float l = 0.f;
#pragma unroll
            for (int mt = 0; mt < 4; ++mt) {
                float p0, p1, p2, p3;
                if (maskit) {
                    const int k = kb0 + mt * 16 + quad * 4;
                    p0 = __expf((k     <= rowq) ? s[mt][j][0] : NINF);
                    p1 = __expf((k + 1 <= rowq) ? s[mt][j][1] : NINF);
                    p2 = __expf((k + 2 <= rowq) ? s[mt][j][2] : NINF);
                    p3 = __expf((k + 3 <= rowq) ? s[mt][j][3] : NINF);
                } else {
                    p0 = __expf(s[mt][j][0]);
                    p1 = __expf(s[mt][j][1]);
                    p2 = __expf(s[mt][j][2]);
                    p3 = __expf(s[mt][j][3]);
                }
                l += (p0 + p1) + (p2 + p3);
                ushort4 pk;
                pk.x = f2bf_fast(p0); pk.y = f2bf_fast(p1);
                pk.z = f2bf_fast(p2); pk.w = f2bf_fast(p3);
                *(ushort4*)(sPw + c16 * SPP + mt * 16 + quad * 4) = pk;
            }
            lsum[j] += l;
#pragma unroll
            for (int ks = 0; ks < 2; ++ks)
                pf[j][ks] = *(const bf16x8*)(sPw + c16 * SPP + ks * 32 + quad * 8);
        }
#pragma unroll
        for (int dt = 0; dt < 4; ++dt)
#pragma unroll
            for (int j = 0; j < 2; ++j) {
                o[dt][j] = __builtin_amdgcn_mfma_f32_16x16x32_bf16(vf[dt][0], pf[j][0], o[dt][j], 0, 0, 0);
                o[dt][j] = __builtin_amdgcn_mfma_f32_16x16x32_bf16(vf[dt][1], pf[j][1], o[dt][j], 0, 0, 0);
            }
    };

    // --- pipelined k-loop (proven idiom): counted vmcnt, raw barriers + asm fences.
    stage(0, 0);
    for (int kt = 0; kt < kiters; ++kt) {
        if (kt + 1 < kiters) {
            stage((kt + 1) & 1, kt + 1);
            asm volatile("s_waitcnt vmcnt(2)" ::: "memory");   // wait stage(kt) only
        } else {
            asm volatile("s_waitcnt vmcnt(0)" ::: "memory");
        }
        __builtin_amdgcn_s_barrier();
        asm volatile("" ::: "memory");
        if (kt * 64 <= qmax) tile(kt & 1, kt);   // wave-uniform guard (short panel skips tail)
        __builtin_amdgcn_s_barrier();
        asm volatile("" ::: "memory");
    }

    // cross-quad reduction of per-lane lsum partials
#pragma unroll
    for (int j = 0; j < 2; ++j) {
        lsum[j] += __shfl_xor(lsum[j], 16);
        lsum[j] += __shfl_xor(lsum[j], 32);
    }

    // epilogue: lane holds q = qw+j*16+c16, d = dt*16+quad*4+r -> float4 stores
    const int b_ = bh >> 4, h_ = bh & 15;
#pragma unroll
    for (int j = 0; j < 2; ++j) {
        const float il = 1.0f / lsum[j];
        const int q = qw + j * 16 + c16;
        float* orow = out + ((size_t)(b_ * TT + q)) * CC + h_ * HS;
#pragma unroll
        for (int dt = 0; dt < 4; ++dt) {
            float4 w;
            w.x = o[dt][j][0] * il; w.y = o[dt][j][1] * il;
            w.z = o[dt][j][2] * il; w.w = o[dt][j][3] * il;
            *(float4*)(orow + dt * 16 + quad * 4) = w;
        }
    }
}

extern "C" void kernel_launch(void* const* d_in, const int* in_sizes, int n_in,
                              void* d_out, int out_size, void* d_ws, size_t ws_size,
                              hipStream_t stream) {
    const float* x    = (const float*)d_in[0];   // [B,T,C] fp32
    const float* W    = (const float*)d_in[1];   // [C,3C] fp32
    const float* bias = (const float*)d_in[2];   // [3C] fp32
    float* out = (float*)d_out;                  // [B,T,C] fp32

    char* ws = (char*)d_ws;
    unsigned short* xb = (unsigned short*)(ws);
    unsigned short* wt = (unsigned short*)(ws + 8388608);
    unsigned short* qb = (unsigned short*)(ws + 8388608 + 6291456);
    unsigned short* kb = (unsigned short*)(ws + 8388608 + 6291456 + 8388608);
    unsigned short* vt = (unsigned short*)(ws + 8388608 + 6291456 + 2 * 8388608);

    k_cast<<<dim3(MM * CC / (256 * 4)), dim3(256), 0, stream>>>(x, xb);
    k_transpose_w<<<dim3(N3C / 32, CC / 32), dim3(256), 0, stream>>>(W, wt);
    k_gemm_qkv<<<dim3(N3C / 128, MM / 128), dim3(256), 0, stream>>>(xb, wt, bias, qb, kb, vt);
    k_attn<<<dim3(8 * 32), dim3(512), 0, stream>>>(qb, kb, vt, out);
}

// Round 10
// 158.129 us; speedup vs baseline: 1.0724x; 1.0724x over previous
//
#include <hip/hip_runtime.h>
#include <hip/hip_bf16.h>
#include <math.h>

// Problem constants (B=2, T=2048, C=1024, NH=16, HS=64)
#define BB   2
#define TT   2048
#define CC   1024
#define NH   16
#define HS   64
#define N3C  3072   // 3*C
#define MM   4096   // B*T

typedef __attribute__((ext_vector_type(8))) short bf16x8;
typedef __attribute__((ext_vector_type(4))) float f32x4;

#define NINF (-__builtin_inff())
#define QSCALE 0.125f   /* folded 1/sqrt(HS); softmax via __expf (natural e) */

__device__ __forceinline__ unsigned short f2bf(float f) {
    unsigned int u = __builtin_bit_cast(unsigned int, f);
    unsigned int r = u + 0x7fffu + ((u >> 16) & 1u);   // RNE
    return (unsigned short)(r >> 16);
}

// cheap round-to-nearest (no tie-to-even) — used only for P (positive, bounded)
__device__ __forceinline__ unsigned short f2bf_fast(float f) {
    unsigned int u = __builtin_bit_cast(unsigned int, f);
    return (unsigned short)((u + 0x8000u) >> 16);
}

// async 16B global -> LDS (dst must be wave-uniform base + lane*16)
__device__ __forceinline__ void gl_lds16(const unsigned short* g, unsigned short* l) {
    __builtin_amdgcn_global_load_lds(
        (const __attribute__((address_space(1))) unsigned int*)g,
        (__attribute__((address_space(3))) unsigned int*)l, 16, 0, 0);
}

// ---------------- cast x (fp32) -> xb (bf16) ----------------
__global__ __launch_bounds__(256) void k_cast(const float* __restrict__ x,
                                              unsigned short* __restrict__ xb) {
    int i = (blockIdx.x * 256 + threadIdx.x) * 4;
    float4 v = *(const float4*)(x + i);
    ushort4 o;
    o.x = f2bf(v.x); o.y = f2bf(v.y); o.z = f2bf(v.z); o.w = f2bf(v.w);
    *(ushort4*)(xb + i) = o;
}

// ---------------- transpose+cast W [K=1024, N=3072] -> Wt [N, K] bf16 ----------------
__global__ __launch_bounds__(256) void k_transpose_w(const float* __restrict__ W,
                                                     unsigned short* __restrict__ Wt) {
    __shared__ float tile[32][33];
    const int n0 = blockIdx.x * 32;
    const int k0 = blockIdx.y * 32;
    const int t = threadIdx.x;
    {
        int kr = t >> 3, ns = (t & 7) * 4;
        float4 v = *(const float4*)(W + (size_t)(k0 + kr) * N3C + n0 + ns);
        tile[kr][ns + 0] = v.x; tile[kr][ns + 1] = v.y;
        tile[kr][ns + 2] = v.z; tile[kr][ns + 3] = v.w;
    }
    __syncthreads();
    {
        int nr = t >> 3, ks = (t & 7) * 4;
        ushort4 o;
        o.x = f2bf(tile[ks + 0][nr]);
        o.y = f2bf(tile[ks + 1][nr]);
        o.z = f2bf(tile[ks + 2][nr]);
        o.w = f2bf(tile[ks + 3][nr]);
        *(ushort4*)(Wt + (size_t)(n0 + nr) * CC + k0 + ks) = o;
    }
}

// ---------------- GEMM v2 (r7-proven): 128x128 tile, BK=64, XOR-swizzled LDS,
// LDS union (sA+sB overlaid by sE epilogue), coalesced epilogues. ----------------
#define EPS 72   // epilogue LDS row stride (elements): 144B, 16B-aligned

__global__ __launch_bounds__(256) void k_gemm_qkv(const unsigned short* __restrict__ xb,
                                                  const unsigned short* __restrict__ wt,
                                                  const float* __restrict__ bias,
                                                  unsigned short* __restrict__ qb,
                                                  unsigned short* __restrict__ kb,
                                                  unsigned short* __restrict__ vt) {
    __shared__ unsigned short smem[4 * 64 * EPS];   // 36864 B union
    unsigned short* sA = smem;                      // [128][64] during k-loop (16 KB)
    unsigned short* sB = smem + 128 * 64;           // [128][64] during k-loop (16 KB)
    unsigned short* sE = smem;                      // 4 x [64][EPS] epilogue staging (36 KB)

    const int t = threadIdx.x;
    const int wave = t >> 6, lane = t & 63;
    const int quad = lane >> 4, c16 = lane & 15;
    const int wm = wave >> 1, wn = wave & 1;
    const int m0 = blockIdx.y * 128;
    const int n0 = blockIdx.x * 128;
    const int sel = n0 >> 10;                 // block-uniform: 0=q, 1=k, 2=v

    f32x4 acc[4][4];
#pragma unroll
    for (int i = 0; i < 4; ++i)
#pragma unroll
        for (int j = 0; j < 4; ++j) acc[i][j] = f32x4{0, 0, 0, 0};

    const int srow_ = t >> 3;                 // 0..31 (row within a 32-row round)
    const int sslot = t & 7;                  // 16B slot within 128B row

    for (int k0 = 0; k0 < CC; k0 += 64) {
        __syncthreads();
#pragma unroll
        for (int rnd = 0; rnd < 4; ++rnd) {
            const int row = rnd * 32 + srow_;
            const int sl = (sslot ^ (row & 7)) * 8;           // pre-swizzled global elem offset
            gl_lds16(xb + (size_t)(m0 + row) * CC + k0 + sl, sA + rnd * 2048 + t * 8);
            gl_lds16(wt + (size_t)(n0 + row) * CC + k0 + sl, sB + rnd * 2048 + t * 8);
        }
        __syncthreads();
#pragma unroll
        for (int ks = 0; ks < 2; ++ks) {
            bf16x8 a[4], b[4];
#pragma unroll
            for (int rt = 0; rt < 4; ++rt)
                a[rt] = *(const bf16x8*)(sA + (wm * 64 + rt * 16 + c16) * 64 +
                                         (((ks * 4 + quad) ^ (c16 & 7)) * 8));
#pragma unroll
            for (int ct = 0; ct < 4; ++ct)
                b[ct] = *(const bf16x8*)(sB + (wn * 64 + ct * 16 + c16) * 64 +
                                         (((ks * 4 + quad) ^ (c16 & 7)) * 8));
#pragma unroll
            for (int rt = 0; rt < 4; ++rt)
#pragma unroll
                for (int ct = 0; ct < 4; ++ct)
                    acc[rt][ct] = __builtin_amdgcn_mfma_f32_16x16x32_bf16(b[ct], a[rt], acc[rt][ct], 0, 0, 0);
        }
    }
    __syncthreads();   // union: epilogue sE overlaps sA/sB

    const int head = ((n0 + wn * 64) >> 6) & 15;           // wave-uniform
    const int bh = (m0 >> 11) * NH + head;
    const int tbase = (m0 & 2047) + wm * 64;               // this wave's 64 t-rows
    if (sel < 2) {
        unsigned short* dst = (sel == 0) ? qb : kb;
        const float sc = (sel == 0) ? QSCALE : 1.0f;
        unsigned short* ew = sE + wave * (64 * EPS);
#pragma unroll
        for (int ct = 0; ct < 4; ++ct) {
            const float4 bv4 = *(const float4*)(bias + n0 + wn * 64 + ct * 16 + quad * 4);
            const int d0 = ct * 16 + quad * 4;
#pragma unroll
            for (int rt = 0; rt < 4; ++rt) {
                ushort4 pk;
                pk.x = f2bf((acc[rt][ct][0] + bv4.x) * sc);
                pk.y = f2bf((acc[rt][ct][1] + bv4.y) * sc);
                pk.z = f2bf((acc[rt][ct][2] + bv4.z) * sc);
                pk.w = f2bf((acc[rt][ct][3] + bv4.w) * sc);
                *(ushort4*)(ew + (rt * 16 + c16) * EPS + d0) = pk;
            }
        }
        const size_t gbase = ((size_t)bh * TT + tbase) * HS;
#pragma unroll
        for (int i = 0; i < 8; ++i) {
            const int trow = i * 8 + (lane >> 3);
            bf16x8 row = *(const bf16x8*)(ew + trow * EPS + (lane & 7) * 8);
            *(bf16x8*)(dst + gbase + (size_t)trow * HS + (lane & 7) * 8) = row;
        }
    } else {
        unsigned short* ew = sE + wave * (64 * EPS);
#pragma unroll
        for (int ct = 0; ct < 4; ++ct) {
            const float4 bv4 = *(const float4*)(bias + n0 + wn * 64 + ct * 16 + quad * 4);
#pragma unroll
            for (int r = 0; r < 4; ++r) {
                const int d = ct * 16 + quad * 4 + r;
                const float bv = ((const float*)&bv4)[r];
#pragma unroll
                for (int rt = 0; rt < 4; ++rt)
                    ew[d * EPS + rt * 16 + c16] = f2bf(acc[rt][ct][r] + bv);
            }
        }
        const size_t vbase = (size_t)bh * HS * TT + tbase;
#pragma unroll
        for (int i = 0; i < 8; ++i) {
            const int d = i * 8 + (lane >> 3);
            bf16x8 row = *(const bf16x8*)(ew + d * EPS + (lane & 7) * 8);
            *(bf16x8*)(vt + vbase + (size_t)d * TT + (lane & 7) * 8) = row;
        }
    }
}

// ---------------- Flash attention v14: MORE WAVE SLOTS PER SIMD.
// Evidence: r7 (1 domain), r8 (2 domains), r9 (j=2) all ~48-53us at 8 waves/CU; r5
// placement remap = exactly 0 delta; all pipes <40%. Model: time = wave-tile work x
// chain latency / wave slots (latency-bound; per-SIMD 68 tiles x ~1700cyc / 2 waves).
// Fix: 1024 four-wave blocks (one 64-row half-panel each, kiters = hp+1, longest
// first). LDS 41984 B -> 3 blocks/CU = 12 waves/CU = 3 waves/SIMD (1.5x slots).
// Block body is r8-v12 VERBATIM (tile/staging/vmcnt(4)/fences/epilogue unchanged);
// only indexing changed and the two-panel ph loop dropped. Total staging volume
// unchanged (each half-panel staged once, as before). ----------------
#define SPP 72   // P row stride (elements): 144B, 16B-aligned

__global__ __launch_bounds__(256) void k_attn(const unsigned short* __restrict__ qb,
                                              const unsigned short* __restrict__ kb,
                                              const unsigned short* __restrict__ vt,
                                              float* __restrict__ out) {
    __shared__ unsigned short sK[2][64 * 64];   // 16 KB: K tile [row t][d], granule-swizzled
    __shared__ unsigned short sV[2][64 * 64];   // 16 KB: V^T tile [row d][t], granule-swizzled
    __shared__ unsigned short sP[4][16 * SPP];  // 9 KB: per-wave P staging (16 rows each)

    const int tid = threadIdx.x;
    const int wave = tid >> 6, lane = tid & 63;
    const int quad = lane >> 4, c16 = lane & 15;
    const int hp = 31 - (int)(blockIdx.x >> 5); // half-panel 0..31, longest work first
    const int bh = blockIdx.x & 31;

    const unsigned short* Qp = qb + (size_t)bh * TT * HS;
    const unsigned short* Kp = kb + (size_t)bh * TT * HS;
    const unsigned short* Vp = vt + (size_t)bh * HS * TT;

    unsigned short* sPw = sP[wave];

    // --- staging (r8-proven): 256 threads cover 64 rows x 8 slots of 16B in 2 rounds;
    // 2 K + 2 V loads per thread per tile. LDS dest LINEAR; XOR swizzle (slot ^= row&7)
    // applied to the per-lane GLOBAL source address (both-sides-or-neither).
    const int srow = tid >> 3;                  // 0..31 (row within round)
    const int ssc = tid & 7;                    // 16B slot
    const int sl = (ssc ^ (srow & 7)) * 8;      // swizzled elem offset ((rnd*32+srow)&7 == srow&7)
    auto stage = [&](int buf, int kt) {
        const int kb0 = kt * 64;
#pragma unroll
        for (int rnd = 0; rnd < 2; ++rnd) {
            const int row = rnd * 32 + srow;
            gl_lds16(Kp + (size_t)(kb0 + row) * HS + sl, &sK[buf][rnd * 2048 + tid * 8]);
            gl_lds16(Vp + (size_t)row * TT + kb0 + sl, &sV[buf][rnd * 2048 + tid * 8]);
        }
    };

    const int b_ = bh >> 4, h_ = bh & 15;
    const int qw = hp * 64 + wave * 16;         // this wave's 16 q-rows
    const int kiters = hp + 1;                  // k-tiles 0..hp cover k <= hp*64+63

    bf16x8 qf[2];
#pragma unroll
    for (int ks = 0; ks < 2; ++ks)
        qf[ks] = *(const bf16x8*)(Qp + (size_t)(qw + c16) * HS + ks * 32 + quad * 8);

    f32x4 o[4];
#pragma unroll
    for (int dt = 0; dt < 4; ++dt) o[dt] = f32x4{0, 0, 0, 0};
    float lsum = 0.f;

    auto tile = [&](int buf, int kt) {
        const int kb0 = kt * 64;
        const unsigned short* Kb = sK[buf];
        const unsigned short* Vb = sV[buf];
        bf16x8 kf[4][2];
#pragma unroll
        for (int mt = 0; mt < 4; ++mt)
#pragma unroll
            for (int ks = 0; ks < 2; ++ks)
                kf[mt][ks] = *(const bf16x8*)(Kb + (mt * 16 + c16) * 64 +
                                              (((ks * 4 + quad) ^ (c16 & 7)) * 8));
        f32x4 s[4];
#pragma unroll
        for (int mt = 0; mt < 4; ++mt) s[mt] = f32x4{0, 0, 0, 0};
#pragma unroll
        for (int mt = 0; mt < 4; ++mt) {
            s[mt] = __builtin_amdgcn_mfma_f32_16x16x32_bf16(kf[mt][0], qf[0], s[mt], 0, 0, 0);
            s[mt] = __builtin_amdgcn_mfma_f32_16x16x32_bf16(kf[mt][1], qf[1], s[mt], 0, 0, 0);
        }
        bf16x8 vf[4][2];
#pragma unroll
        for (int dt = 0; dt < 4; ++dt)
#pragma unroll
            for (int ks = 0; ks < 2; ++ks)
                vf[dt][ks] = *(const bf16x8*)(Vb + (dt * 16 + c16) * 64 +
                                              (((ks * 4 + quad) ^ (c16 & 7)) * 8));
        const bool maskit = (kb0 + 63 > qw);
        const int rowq = qw + c16;
        float l = 0.f;
#pragma unroll
        for (int mt = 0; mt < 4; ++mt) {
            float p0, p1, p2, p3;
            if (maskit) {
                const int k = kb0 + mt * 16 + quad * 4;
                p0 = __expf((k     <= rowq) ? s[mt][0] : NINF);
                p1 = __expf((k + 1 <= rowq) ? s[mt][1] : NINF);
                p2 = __expf((k + 2 <= rowq) ? s[mt][2] : NINF);
                p3 = __expf((k + 3 <= rowq) ? s[mt][3] : NINF);
            } else {
                p0 = __expf(s[mt][0]);
                p1 = __expf(s[mt][1]);
                p2 = __expf(s[mt][2]);
                p3 = __expf(s[mt][3]);
            }
            l += (p0 + p1) + (p2 + p3);
            ushort4 pk;
            pk.x = f2bf_fast(p0); pk.y = f2bf_fast(p1);
            pk.z = f2bf_fast(p2); pk.w = f2bf_fast(p3);
            *(ushort4*)(sPw + c16 * SPP + mt * 16 + quad * 4) = pk;
        }
        lsum += l;
        bf16x8 pf[2];
#pragma unroll
        for (int ks = 0; ks < 2; ++ks)
            pf[ks] = *(const bf16x8*)(sPw + c16 * SPP + ks * 32 + quad * 8);
#pragma unroll
        for (int dt = 0; dt < 4; ++dt) {
            o[dt] = __builtin_amdgcn_mfma_f32_16x16x32_bf16(vf[dt][0], pf[0], o[dt], 0, 0, 0);
            o[dt] = __builtin_amdgcn_mfma_f32_16x16x32_bf16(vf[dt][1], pf[1], o[dt], 0, 0, 0);
        }
    };

    // --- pipelined k-loop (proven idiom): counted vmcnt, raw barriers + asm fences.
    stage(0, 0);
    for (int kt = 0; kt < kiters; ++kt) {
        if (kt + 1 < kiters) {
            stage((kt + 1) & 1, kt + 1);
            asm volatile("s_waitcnt vmcnt(4)" ::: "memory");   // wait stage(kt) only
        } else {
            asm volatile("s_waitcnt vmcnt(0)" ::: "memory");
        }
        __builtin_amdgcn_s_barrier();
        asm volatile("" ::: "memory");
        tile(kt & 1, kt);                       // no tiles skipped: all kt <= hp needed
        __builtin_amdgcn_s_barrier();
        asm volatile("" ::: "memory");
    }

    lsum += __shfl_xor(lsum, 16);
    lsum += __shfl_xor(lsum, 32);

    const float il = 1.0f / lsum;
    const int q = qw + c16;
    float* orow = out + ((size_t)(b_ * TT + q)) * CC + h_ * HS;
#pragma unroll
    for (int dt = 0; dt < 4; ++dt) {
        float4 w;
        w.x = o[dt][0] * il; w.y = o[dt][1] * il;
        w.z = o[dt][2] * il; w.w = o[dt][3] * il;
        *(float4*)(orow + dt * 16 + quad * 4) = w;
    }
}

extern "C" void kernel_launch(void* const* d_in, const int* in_sizes, int n_in,
                              void* d_out, int out_size, void* d_ws, size_t ws_size,
                              hipStream_t stream) {
    const float* x    = (const float*)d_in[0];   // [B,T,C] fp32
    const float* W    = (const float*)d_in[1];   // [C,3C] fp32
    const float* bias = (const float*)d_in[2];   // [3C] fp32
    float* out = (float*)d_out;                  // [B,T,C] fp32

    char* ws = (char*)d_ws;
    unsigned short* xb = (unsigned short*)(ws);
    unsigned short* wt = (unsigned short*)(ws + 8388608);
    unsigned short* qb = (unsigned short*)(ws + 8388608 + 6291456);
    unsigned short* kb = (unsigned short*)(ws + 8388608 + 6291456 + 8388608);
    unsigned short* vt = (unsigned short*)(ws + 8388608 + 6291456 + 2 * 8388608);

    k_cast<<<dim3(MM * CC / (256 * 4)), dim3(256), 0, stream>>>(x, xb);
    k_transpose_w<<<dim3(N3C / 32, CC / 32), dim3(256), 0, stream>>>(W, wt);
    k_gemm_qkv<<<dim3(N3C / 128, MM / 128), dim3(256), 0, stream>>>(xb, wt, bias, qb, kb, vt);
    k_attn<<<dim3(32 * 32), dim3(256), 0, stream>>>(qb, kb, vt, out);
}

// Round 11
// 149.950 us; speedup vs baseline: 1.1309x; 1.0545x over previous
//
#include <hip/hip_runtime.h>
#include <hip/hip_bf16.h>
#include <math.h>

// Problem constants (B=2, T=2048, C=1024, NH=16, HS=64)
#define BB   2
#define TT   2048
#define CC   1024
#define NH   16
#define HS   64
#define N3C  3072   // 3*C
#define MM   4096   // B*T

typedef __attribute__((ext_vector_type(8))) short bf16x8;
typedef __attribute__((ext_vector_type(4))) float f32x4;

#define NINF (-__builtin_inff())
#define QSCALE 0.125f   /* folded 1/sqrt(HS); softmax via __expf (natural e) */

__device__ __forceinline__ unsigned short f2bf(float f) {
    unsigned int u = __builtin_bit_cast(unsigned int, f);
    unsigned int r = u + 0x7fffu + ((u >> 16) & 1u);   // RNE
    return (unsigned short)(r >> 16);
}

// cheap round-to-nearest (no tie-to-even) — used only for P (positive, bounded)
__device__ __forceinline__ unsigned short f2bf_fast(float f) {
    unsigned int u = __builtin_bit_cast(unsigned int, f);
    return (unsigned short)((u + 0x8000u) >> 16);
}

// async 16B global -> LDS (dst must be wave-uniform base + lane*16)
__device__ __forceinline__ void gl_lds16(const unsigned short* g, unsigned short* l) {
    __builtin_amdgcn_global_load_lds(
        (const __attribute__((address_space(1))) unsigned int*)g,
        (__attribute__((address_space(3))) unsigned int*)l, 16, 0, 0);
}

// ---------------- cast x (fp32) -> xb (bf16) ----------------
__global__ __launch_bounds__(256) void k_cast(const float* __restrict__ x,
                                              unsigned short* __restrict__ xb) {
    int i = (blockIdx.x * 256 + threadIdx.x) * 4;
    float4 v = *(const float4*)(x + i);
    ushort4 o;
    o.x = f2bf(v.x); o.y = f2bf(v.y); o.z = f2bf(v.z); o.w = f2bf(v.w);
    *(ushort4*)(xb + i) = o;
}

// ---------------- transpose+cast W [K=1024, N=3072] -> Wt [N, K] bf16 ----------------
__global__ __launch_bounds__(256) void k_transpose_w(const float* __restrict__ W,
                                                     unsigned short* __restrict__ Wt) {
    __shared__ float tile[32][33];
    const int n0 = blockIdx.x * 32;
    const int k0 = blockIdx.y * 32;
    const int t = threadIdx.x;
    {
        int kr = t >> 3, ns = (t & 7) * 4;
        float4 v = *(const float4*)(W + (size_t)(k0 + kr) * N3C + n0 + ns);
        tile[kr][ns + 0] = v.x; tile[kr][ns + 1] = v.y;
        tile[kr][ns + 2] = v.z; tile[kr][ns + 3] = v.w;
    }
    __syncthreads();
    {
        int nr = t >> 3, ks = (t & 7) * 4;
        ushort4 o;
        o.x = f2bf(tile[ks + 0][nr]);
        o.y = f2bf(tile[ks + 1][nr]);
        o.z = f2bf(tile[ks + 2][nr]);
        o.w = f2bf(tile[ks + 3][nr]);
        *(ushort4*)(Wt + (size_t)(n0 + nr) * CC + k0 + ks) = o;
    }
}

// ---------------- GEMM v3: r7 structure + counted-vmcnt DOUBLE-BUFFER pipeline.
// Evidence (r10): conflicts fixed (229K) but MfmaUtil stuck at 21% -- the 2-barrier
// k-loop drains vmcnt(0) before every s_barrier (compiler-emitted), exposing the full
// staging latency each of 16 steps (~50% dead time). Fix: the attn-proven idiom
// (in this session since r2): stage(it+1) into the other buffer BEFORE waiting;
// asm vmcnt(8) waits only stage(it)'s 8 loads/thread; raw barriers + asm fences
// (s_barrier is NOT a compiler fence). LDS: 2 x (sA+sB) = 64 KB, sE epilogue unions
// inside. Compute/swizzle/epilogue byte-identical to r7-proven code. ----------------
#define EPS 72   // epilogue LDS row stride (elements): 144B, 16B-aligned

__global__ __launch_bounds__(256) void k_gemm_qkv(const unsigned short* __restrict__ xb,
                                                  const unsigned short* __restrict__ wt,
                                                  const float* __restrict__ bias,
                                                  unsigned short* __restrict__ qb,
                                                  unsigned short* __restrict__ kb,
                                                  unsigned short* __restrict__ vt) {
    __shared__ unsigned short smem[32768];          // 64 KB: 2 bufs x (sA 8192 + sB 8192 elems)
    unsigned short* sE = smem;                      // 4 x [64][EPS] epilogue staging (36 KB, union)

    const int t = threadIdx.x;
    const int wave = t >> 6, lane = t & 63;
    const int quad = lane >> 4, c16 = lane & 15;
    const int wm = wave >> 1, wn = wave & 1;
    const int m0 = blockIdx.y * 128;
    const int n0 = blockIdx.x * 128;
    const int sel = n0 >> 10;                 // block-uniform: 0=q, 1=k, 2=v

    f32x4 acc[4][4];
#pragma unroll
    for (int i = 0; i < 4; ++i)
#pragma unroll
        for (int j = 0; j < 4; ++j) acc[i][j] = f32x4{0, 0, 0, 0};

    const int srow_ = t >> 3;                 // 0..31 (row within a 32-row round)
    const int sslot = t & 7;                  // 16B slot within 128B row

    // stage k-tile (BK=64) into buffer b: LINEAR LDS dest, XOR-swizzled GLOBAL source
    auto stage = [&](int b, int k0) {
        unsigned short* dA = smem + b * 16384;
        unsigned short* dB = smem + b * 16384 + 8192;
#pragma unroll
        for (int rnd = 0; rnd < 4; ++rnd) {
            const int row = rnd * 32 + srow_;
            const int sl = (sslot ^ (row & 7)) * 8;           // pre-swizzled global elem offset
            gl_lds16(xb + (size_t)(m0 + row) * CC + k0 + sl, dA + rnd * 2048 + t * 8);
            gl_lds16(wt + (size_t)(n0 + row) * CC + k0 + sl, dB + rnd * 2048 + t * 8);
        }
    };

    stage(0, 0);
    for (int it = 0; it < 16; ++it) {
        if (it + 1 < 16) {
            stage((it + 1) & 1, (it + 1) * 64);
            asm volatile("s_waitcnt vmcnt(8)" ::: "memory");   // wait stage(it) only
        } else {
            asm volatile("s_waitcnt vmcnt(0)" ::: "memory");
        }
        __builtin_amdgcn_s_barrier();
        asm volatile("" ::: "memory");
        const unsigned short* sA = smem + (it & 1) * 16384;
        const unsigned short* sB = smem + (it & 1) * 16384 + 8192;
#pragma unroll
        for (int ks = 0; ks < 2; ++ks) {
            bf16x8 a[4], b[4];
#pragma unroll
            for (int rt = 0; rt < 4; ++rt)
                a[rt] = *(const bf16x8*)(sA + (wm * 64 + rt * 16 + c16) * 64 +
                                         (((ks * 4 + quad) ^ (c16 & 7)) * 8));
#pragma unroll
            for (int ct = 0; ct < 4; ++ct)
                b[ct] = *(const bf16x8*)(sB + (wn * 64 + ct * 16 + c16) * 64 +
                                         (((ks * 4 + quad) ^ (c16 & 7)) * 8));
#pragma unroll
            for (int rt = 0; rt < 4; ++rt)
#pragma unroll
                for (int ct = 0; ct < 4; ++ct)
                    acc[rt][ct] = __builtin_amdgcn_mfma_f32_16x16x32_bf16(b[ct], a[rt], acc[rt][ct], 0, 0, 0);
        }
        __builtin_amdgcn_s_barrier();          // protect buf (it+1)&1 from next stage overwrite
        asm volatile("" ::: "memory");
    }
    __syncthreads();   // union: epilogue sE overlaps the k-loop buffers

    const int head = ((n0 + wn * 64) >> 6) & 15;           // wave-uniform
    const int bh = (m0 >> 11) * NH + head;
    const int tbase = (m0 & 2047) + wm * 64;               // this wave's 64 t-rows
    if (sel < 2) {
        unsigned short* dst = (sel == 0) ? qb : kb;
        const float sc = (sel == 0) ? QSCALE : 1.0f;
        unsigned short* ew = sE + wave * (64 * EPS);
#pragma unroll
        for (int ct = 0; ct < 4; ++ct) {
            const float4 bv4 = *(const float4*)(bias + n0 + wn * 64 + ct * 16 + quad * 4);
            const int d0 = ct * 16 + quad * 4;
#pragma unroll
            for (int rt = 0; rt < 4; ++rt) {
                ushort4 pk;
                pk.x = f2bf((acc[rt][ct][0] + bv4.x) * sc);
                pk.y = f2bf((acc[rt][ct][1] + bv4.y) * sc);
                pk.z = f2bf((acc[rt][ct][2] + bv4.z) * sc);
                pk.w = f2bf((acc[rt][ct][3] + bv4.w) * sc);
                *(ushort4*)(ew + (rt * 16 + c16) * EPS + d0) = pk;
            }
        }
        const size_t gbase = ((size_t)bh * TT + tbase) * HS;
#pragma unroll
        for (int i = 0; i < 8; ++i) {
            const int trow = i * 8 + (lane >> 3);
            bf16x8 row = *(const bf16x8*)(ew + trow * EPS + (lane & 7) * 8);
            *(bf16x8*)(dst + gbase + (size_t)trow * HS + (lane & 7) * 8) = row;
        }
    } else {
        unsigned short* ew = sE + wave * (64 * EPS);
#pragma unroll
        for (int ct = 0; ct < 4; ++ct) {
            const float4 bv4 = *(const float4*)(bias + n0 + wn * 64 + ct * 16 + quad * 4);
#pragma unroll
            for (int r = 0; r < 4; ++r) {
                const int d = ct * 16 + quad * 4 + r;
                const float bv = ((const float*)&bv4)[r];
#pragma unroll
                for (int rt = 0; rt < 4; ++rt)
                    ew[d * EPS + rt * 16 + c16] = f2bf(acc[rt][ct][r] + bv);
            }
        }
        const size_t vbase = (size_t)bh * HS * TT + tbase;
#pragma unroll
        for (int i = 0; i < 8; ++i) {
            const int d = i * 8 + (lane >> 3);
            bf16x8 row = *(const bf16x8*)(ew + d * EPS + (lane & 7) * 8);
            *(bf16x8*)(vt + vbase + (size_t)d * TT + (lane & 7) * 8) = row;
        }
    }
}

// ---------------- Flash attention v14 (r10-proven, unchanged): 1024 four-wave blocks,
// one 64-row half-panel each, 3 blocks/CU = 12 waves/CU; counted vmcnt pipeline. ----------------
#define SPP 72   // P row stride (elements): 144B, 16B-aligned

__global__ __launch_bounds__(256) void k_attn(const unsigned short* __restrict__ qb,
                                              const unsigned short* __restrict__ kb,
                                              const unsigned short* __restrict__ vt,
                                              float* __restrict__ out) {
    __shared__ unsigned short sK[2][64 * 64];   // 16 KB: K tile [row t][d], granule-swizzled
    __shared__ unsigned short sV[2][64 * 64];   // 16 KB: V^T tile [row d][t], granule-swizzled
    __shared__ unsigned short sP[4][16 * SPP];  // 9 KB: per-wave P staging (16 rows each)

    const int tid = threadIdx.x;
    const int wave = tid >> 6, lane = tid & 63;
    const int quad = lane >> 4, c16 = lane & 15;
    const int hp = 31 - (int)(blockIdx.x >> 5); // half-panel 0..31, longest work first
    const int bh = blockIdx.x & 31;

    const unsigned short* Qp = qb + (size_t)bh * TT * HS;
    const unsigned short* Kp = kb + (size_t)bh * TT * HS;
    const unsigned short* Vp = vt + (size_t)bh * HS * TT;

    unsigned short* sPw = sP[wave];

    const int srow = tid >> 3;                  // 0..31 (row within round)
    const int ssc = tid & 7;                    // 16B slot
    const int sl = (ssc ^ (srow & 7)) * 8;      // swizzled elem offset ((rnd*32+srow)&7 == srow&7)
    auto stage = [&](int buf, int kt) {
        const int kb0 = kt * 64;
#pragma unroll
        for (int rnd = 0; rnd < 2; ++rnd) {
            const int row = rnd * 32 + srow;
            gl_lds16(Kp + (size_t)(kb0 + row) * HS + sl, &sK[buf][rnd * 2048 + tid * 8]);
            gl_lds16(Vp + (size_t)row * TT + kb0 + sl, &sV[buf][rnd * 2048 + tid * 8]);
        }
    };

    const int b_ = bh >> 4, h_ = bh & 15;
    const int qw = hp * 64 + wave * 16;         // this wave's 16 q-rows
    const int kiters = hp + 1;                  // k-tiles 0..hp cover k <= hp*64+63

    bf16x8 qf[2];
#pragma unroll
    for (int ks = 0; ks < 2; ++ks)
        qf[ks] = *(const bf16x8*)(Qp + (size_t)(qw + c16) * HS + ks * 32 + quad * 8);

    f32x4 o[4];
#pragma unroll
    for (int dt = 0; dt < 4; ++dt) o[dt] = f32x4{0, 0, 0, 0};
    float lsum = 0.f;

    auto tile = [&](int buf, int kt) {
        const int kb0 = kt * 64;
        const unsigned short* Kb = sK[buf];
        const unsigned short* Vb = sV[buf];
        bf16x8 kf[4][2];
#pragma unroll
        for (int mt = 0; mt < 4; ++mt)
#pragma unroll
            for (int ks = 0; ks < 2; ++ks)
                kf[mt][ks] = *(const bf16x8*)(Kb + (mt * 16 + c16) * 64 +
                                              (((ks * 4 + quad) ^ (c16 & 7)) * 8));
        f32x4 s[4];
#pragma unroll
        for (int mt = 0; mt < 4; ++mt) s[mt] = f32x4{0, 0, 0, 0};
#pragma unroll
        for (int mt = 0; mt < 4; ++mt) {
            s[mt] = __builtin_amdgcn_mfma_f32_16x16x32_bf16(kf[mt][0], qf[0], s[mt], 0, 0, 0);
            s[mt] = __builtin_amdgcn_mfma_f32_16x16x32_bf16(kf[mt][1], qf[1], s[mt], 0, 0, 0);
        }
        bf16x8 vf[4][2];
#pragma unroll
        for (int dt = 0; dt < 4; ++dt)
#pragma unroll
            for (int ks = 0; ks < 2; ++ks)
                vf[dt][ks] = *(const bf16x8*)(Vb + (dt * 16 + c16) * 64 +
                                              (((ks * 4 + quad) ^ (c16 & 7)) * 8));
        const bool maskit = (kb0 + 63 > qw);
        const int rowq = qw + c16;
        float l = 0.f;
#pragma unroll
        for (int mt = 0; mt < 4; ++mt) {
            float p0, p1, p2, p3;
            if (maskit) {
                const int k = kb0 + mt * 16 + quad * 4;
                p0 = __expf((k     <= rowq) ? s[mt][0] : NINF);
                p1 = __expf((k + 1 <= rowq) ? s[mt][1] : NINF);
                p2 = __expf((k + 2 <= rowq) ? s[mt][2] : NINF);
                p3 = __expf((k + 3 <= rowq) ? s[mt][3] : NINF);
            } else {
                p0 = __expf(s[mt][0]);
                p1 = __expf(s[mt][1]);
                p2 = __expf(s[mt][2]);
                p3 = __expf(s[mt][3]);
            }
            l += (p0 + p1) + (p2 + p3);
            ushort4 pk;
            pk.x = f2bf_fast(p0); pk.y = f2bf_fast(p1);
            pk.z = f2bf_fast(p2); pk.w = f2bf_fast(p3);
            *(ushort4*)(sPw + c16 * SPP + mt * 16 + quad * 4) = pk;
        }
        lsum += l;
        bf16x8 pf[2];
#pragma unroll
        for (int ks = 0; ks < 2; ++ks)
            pf[ks] = *(const bf16x8*)(sPw + c16 * SPP + ks * 32 + quad * 8);
#pragma unroll
        for (int dt = 0; dt < 4; ++dt) {
            o[dt] = __builtin_amdgcn_mfma_f32_16x16x32_bf16(vf[dt][0], pf[0], o[dt], 0, 0, 0);
            o[dt] = __builtin_amdgcn_mfma_f32_16x16x32_bf16(vf[dt][1], pf[1], o[dt], 0, 0, 0);
        }
    };

    stage(0, 0);
    for (int kt = 0; kt < kiters; ++kt) {
        if (kt + 1 < kiters) {
            stage((kt + 1) & 1, kt + 1);
            asm volatile("s_waitcnt vmcnt(4)" ::: "memory");   // wait stage(kt) only
        } else {
            asm volatile("s_waitcnt vmcnt(0)" ::: "memory");
        }
        __builtin_amdgcn_s_barrier();
        asm volatile("" ::: "memory");
        tile(kt & 1, kt);                       // no tiles skipped: all kt <= hp needed
        __builtin_amdgcn_s_barrier();
        asm volatile("" ::: "memory");
    }

    lsum += __shfl_xor(lsum, 16);
    lsum += __shfl_xor(lsum, 32);

    const float il = 1.0f / lsum;
    const int q = qw + c16;
    float* orow = out + ((size_t)(b_ * TT + q)) * CC + h_ * HS;
#pragma unroll
    for (int dt = 0; dt < 4; ++dt) {
        float4 w;
        w.x = o[dt][0] * il; w.y = o[dt][1] * il;
        w.z = o[dt][2] * il; w.w = o[dt][3] * il;
        *(float4*)(orow + dt * 16 + quad * 4) = w;
    }
}

extern "C" void kernel_launch(void* const* d_in, const int* in_sizes, int n_in,
                              void* d_out, int out_size, void* d_ws, size_t ws_size,
                              hipStream_t stream) {
    const float* x    = (const float*)d_in[0];   // [B,T,C] fp32
    const float* W    = (const float*)d_in[1];   // [C,3C] fp32
    const float* bias = (const float*)d_in[2];   // [3C] fp32
    float* out = (float*)d_out;                  // [B,T,C] fp32

    char* ws = (char*)d_ws;
    unsigned short* xb = (unsigned short*)(ws);
    unsigned short* wt = (unsigned short*)(ws + 8388608);
    unsigned short* qb = (unsigned short*)(ws + 8388608 + 6291456);
    unsigned short* kb = (unsigned short*)(ws + 8388608 + 6291456 + 8388608);
    unsigned short* vt = (unsigned short*)(ws + 8388608 + 6291456 + 2 * 8388608);

    k_cast<<<dim3(MM * CC / (256 * 4)), dim3(256), 0, stream>>>(x, xb);
    k_transpose_w<<<dim3(N3C / 32, CC / 32), dim3(256), 0, stream>>>(W, wt);
    k_gemm_qkv<<<dim3(N3C / 128, MM / 128), dim3(256), 0, stream>>>(xb, wt, bias, qb, kb, vt);
    k_attn<<<dim3(32 * 32), dim3(256), 0, stream>>>(qb, kb, vt, out);
}